// Round 7
// baseline (2935.259 us; speedup 1.0000x reference)
//
#include <hip/hip_runtime.h>
#include <hip/hip_bf16.h>
#include <stdint.h>

using bf16 = __hip_bfloat16;
typedef __attribute__((ext_vector_type(8))) short bf16x8;
typedef __attribute__((ext_vector_type(8))) unsigned short u16x8;
typedef __attribute__((ext_vector_type(4))) float f32x4;

#define B_ROWS 16384
#define D_DIM  1024
#define NLAYER 18

__device__ inline void gload_lds16(const bf16* g, bf16* l) {
    __builtin_amdgcn_global_load_lds(
        (const __attribute__((address_space(1))) void*)g,
        (__attribute__((address_space(3))) void*)l, 16, 0, 0);
}

__device__ inline unsigned short f2bf_bits(float f) {
    bf16 h = __float2bfloat16(f);
    return *reinterpret_cast<unsigned short*>(&h);
}
__device__ inline float bfbits2f(unsigned short u) {
    unsigned int x = ((unsigned int)u) << 16;
    return __uint_as_float(x);
}
// double-bf16 split: v ~= hi + lo with rel err ~2^-18
__device__ inline void split_bf(float v, unsigned short& hi, unsigned short& lo) {
    hi = f2bf_bits(v);
    float hf = bfbits2f(hi);
    lo = f2bf_bits(v - hf);
}

// ---------------------------------------------------------------------------
// Weff[l][o][i] = (wq-8)*scale + sum_r lora_b[l][o][r]*lora_a[l][r][i]
// stored as hi/lo bf16 pair. One block per (l, 8-row group): lora_a float4
// reads amortized over 8 output rows (L2 traffic 2.4GB -> 0.3GB vs round 6).
// ---------------------------------------------------------------------------
__global__ __launch_bounds__(256)
void build_weff(const int* __restrict__ wq, const float* __restrict__ scales,
                const float* __restrict__ lora_a, const float* __restrict__ lora_b,
                bf16* __restrict__ weff_h, bf16* __restrict__ weff_l)
{
    const int bb = blockIdx.x;           // 18 * 128
    const int l  = bb >> 7;
    const int o0 = (bb & 127) * 8;
    __shared__ float bsh[8][32];
    {
        const int oo = threadIdx.x >> 5, rr = threadIdx.x & 31;
        bsh[oo][rr] = lora_b[((size_t)l * 1024 + o0 + oo) * 32 + rr];
    }
    __syncthreads();

    const float* abase = lora_a + (size_t)l * 32 * 1024;
    const int i0 = threadIdx.x * 4;      // 256 threads x 4 = 1024 i's
    float acc[8][4] = {};
    #pragma unroll 4
    for (int r = 0; r < 32; ++r) {
        float4 av = *reinterpret_cast<const float4*>(abase + (size_t)r * 1024 + i0);
        #pragma unroll
        for (int o = 0; o < 8; ++o) {
            const float br = bsh[o][r];
            acc[o][0] += br * av.x; acc[o][1] += br * av.y;
            acc[o][2] += br * av.z; acc[o][3] += br * av.w;
        }
    }
    #pragma unroll
    for (int o = 0; o < 8; ++o) {
        const size_t row = (size_t)l * 1024 + o0 + o;
        int4 q = *reinterpret_cast<const int4*>(wq + row * 1024 + i0);
        const float sc = scales[row * 64 + (i0 >> 4)];
        float w0 = (q.x - 8) * sc + acc[o][0];
        float w1 = (q.y - 8) * sc + acc[o][1];
        float w2 = (q.z - 8) * sc + acc[o][2];
        float w3 = (q.w - 8) * sc + acc[o][3];
        ushort4 uh, ul;
        split_bf(w0, uh.x, ul.x); split_bf(w1, uh.y, ul.y);
        split_bf(w2, uh.z, ul.z); split_bf(w3, uh.w, ul.w);
        *reinterpret_cast<ushort4*>(weff_h + row * 1024 + i0) = uh;
        *reinterpret_cast<ushort4*>(weff_l + row * 1024 + i0) = ul;
    }
}

// ---------------------------------------------------------------------------
// x f32 -> hi/lo bf16 pair
// ---------------------------------------------------------------------------
__global__ __launch_bounds__(256)
void cast_split(const float* __restrict__ x, bf16* __restrict__ yh, bf16* __restrict__ yl)
{
    size_t i = ((size_t)blockIdx.x * 256 + threadIdx.x) * 4;
    float4 v = *reinterpret_cast<const float4*>(x + i);
    ushort4 uh, ul;
    split_bf(v.x, uh.x, ul.x); split_bf(v.y, uh.y, ul.y);
    split_bf(v.z, uh.z, ul.z); split_bf(v.w, uh.w, ul.w);
    *reinterpret_cast<ushort4*>(yh + i) = uh;
    *reinterpret_cast<ushort4*>(yl + i) = ul;
}

// ---------------------------------------------------------------------------
// GEMM, double-bf16 operands, 3 MFMA products: acc += Ah*Wh + Ah*Wl + Al*Wh
// 128x128 tile, BK=32, 4 waves. A-fragments loaded DIRECTLY global->VGPR
// (each lane's 16B is its MFMA fragment; rows shared across n-blocks are
// L2-resident thanks to the XCD swizzle). Only W is LDS-staged (2-deep,
// counted vmcnt: steady state = 4 W-stage + 8 A-loads in flight -> vmcnt(12)).
// LDS pipe traffic halved vs round 6 (the measured bottleneck).
// MODE 0: relu -> pair out;  MODE 1: +res -> pair out;  MODE 2: +res -> f32
// ---------------------------------------------------------------------------
#define SCHED0 __builtin_amdgcn_sched_barrier(0)

template<int MODE>
__global__ __launch_bounds__(256)
void qgemm3(const bf16* __restrict__ AH, const bf16* __restrict__ AL,
            const bf16* __restrict__ WH, const bf16* __restrict__ WL,
            const float* __restrict__ bias,
            const bf16* __restrict__ RH, const bf16* __restrict__ RL,
            bf16* __restrict__ OH, bf16* __restrict__ OL,
            float* __restrict__ Of)
{
    // 64 KiB: first 32 KiB = W double-buffer (2 x {WH 4096, WL 4096} elems);
    // whole 64 KiB reused as epilogue f32 scratch (4 waves x 16 KiB).
    __shared__ __align__(16) char smem_raw[65536];
    bf16* smem = reinterpret_cast<bf16*>(smem_raw);

    // T1: chunked XCD swizzle. nwg = 1024 (8 n-tiles fast, 128 m-tiles).
    const int b  = blockIdx.x;
    const int sb = ((b & 7) << 7) | (b >> 3);
    const int n0 = (sb & 7) * 128;
    const int m0 = (sb >> 3) * 128;

    const int tid  = threadIdx.x;
    const int wave = tid >> 6;
    const int lane = tid & 63;
    const int wr = wave >> 1, wc = wave & 1;

    const int rl = lane >> 2;          // staging: row within 16-row segment
    const int ps = lane & 3;           // staging: phys 16B slot
    const int fr = lane & 15;          // fragment row
    const int fq = lane >> 4;          // fragment k-chunk (16B unit)

    f32x4 acc[4][4] = {};

    // W staging: per wave 2 segments x 2 tensors = 4 global_load_lds
    auto wstage = [&](int buf, int k0) {
        bf16* base = smem + buf * 8192;
        #pragma unroll
        for (int t = 0; t < 2; ++t) {
            int s = wave * 2 + t;                   // segment 0..7 (wave-uniform)
            int r = s * 16 + rl;
            int q = ps ^ (r & 3) ^ ((r >> 2) & 3);  // pre-swizzled global chunk
            size_t gb = (size_t)(n0 + r) * D_DIM + k0 + q * 8;
            bf16* dst = base + s * 512;             // HW adds lane*16B
            gload_lds16(WH + gb, dst);
            gload_lds16(WL + gb, dst + 4096);
        }
    };
    // A fragment loads: global -> VGPR, 8 loads (4 m-frags x hi/lo)
    auto aload = [&](bf16x8* arh, bf16x8* arl, int kcol) {
        #pragma unroll
        for (int m = 0; m < 4; ++m) {
            size_t ga = (size_t)(m0 + wr * 64 + m * 16 + fr) * D_DIM + kcol + fq * 8;
            arh[m] = *reinterpret_cast<const bf16x8*>(AH + ga);
            arl[m] = *reinterpret_cast<const bf16x8*>(AL + ga);
        }
    };
    // one K-step: barrier (W resident); read W frags; drain+barrier;
    // stage W(kt+2); MFMA cluster with in-reg A frags.
    auto kstep = [&](const bf16x8* ah, const bf16x8* al, int buf, bool dostage, int knext) {
        __builtin_amdgcn_s_barrier();
        const bf16* tb = smem + buf * 8192;
        bf16x8 wfh[4], wfl[4];
        #pragma unroll
        for (int n = 0; n < 4; ++n) {
            int R = wc * 64 + n * 16 + fr;
            int p = fq ^ (R & 3) ^ ((R >> 2) & 3);
            int off = R * 32 + p * 8;
            wfh[n] = *reinterpret_cast<const bf16x8*>(tb + off);
            wfl[n] = *reinterpret_cast<const bf16x8*>(tb + 4096 + off);
        }
        SCHED0;
        asm volatile("s_waitcnt lgkmcnt(0)" ::: "memory");
        SCHED0;
        __builtin_amdgcn_s_barrier();
        if (dostage) wstage(buf, knext);
        __builtin_amdgcn_s_setprio(1);
        #pragma unroll
        for (int m = 0; m < 4; ++m)
            #pragma unroll
            for (int n = 0; n < 4; ++n) {
                acc[m][n] = __builtin_amdgcn_mfma_f32_16x16x32_bf16(ah[m], wfh[n], acc[m][n], 0, 0, 0);
                acc[m][n] = __builtin_amdgcn_mfma_f32_16x16x32_bf16(ah[m], wfl[n], acc[m][n], 0, 0, 0);
                acc[m][n] = __builtin_amdgcn_mfma_f32_16x16x32_bf16(al[m], wfh[n], acc[m][n], 0, 0, 0);
            }
        __builtin_amdgcn_s_setprio(0);
    };

    bf16x8 a0h[4], a0l[4], a1h[4], a1l[4];

    // ---- prologue: W 2-deep, A(0) in regs
    wstage(0, 0);
    aload(a0h, a0l, 0);
    wstage(1, 32);

    #pragma unroll 1
    for (int it = 0; it < 16; ++it) {
        const int kt0 = 2 * it;
        // even step kt0 (buf 0, A set 0); prefetch A(kt0+1) into set 1
        aload(a1h, a1l, (kt0 + 1) * 32);
        SCHED0;
        asm volatile("s_waitcnt vmcnt(12)" ::: "memory");  // W(kt0)+A(kt0) done
        SCHED0;
        kstep(a0h, a0l, 0, kt0 <= 29, (kt0 + 2) * 32);

        const int kt1 = kt0 + 1;
        // odd step kt1 (buf 1, A set 1); prefetch A(kt1+1) into set 0
        if (it < 15) {
            aload(a0h, a0l, (kt1 + 1) * 32);
            SCHED0;
            asm volatile("s_waitcnt vmcnt(12)" ::: "memory");
            SCHED0;
        } else {
            SCHED0;
            asm volatile("s_waitcnt vmcnt(0)" ::: "memory");
            SCHED0;
        }
        kstep(a1h, a1l, 1, kt1 <= 29, (kt1 + 2) * 32);
    }

    // ---- Epilogue via LDS transpose (wave-private 16 KiB f32 regions).
    // C/D layout: col = lane&15 (=fr), row = (lane>>4)*4 + j.
    const int crow4 = (lane >> 4) * 4;
    float* cwave = reinterpret_cast<float*>(smem_raw) + wave * 4096;

    #pragma unroll
    for (int n = 0; n < 4; ++n) {
        const float bv = bias[n0 + wc * 64 + n * 16 + fr];
        const int lcol = n * 16 + fr;                     // local col 0..63
        const int chunk = lcol >> 2;
        #pragma unroll
        for (int m = 0; m < 4; ++m) {
            #pragma unroll
            for (int j = 0; j < 4; ++j) {
                const int lrow = m * 16 + crow4 + j;      // local row 0..63
                float v = acc[m][n][j] + bv;
                if (MODE == 0) v = v > 0.f ? v : 0.f;
                cwave[lrow * 64 + (chunk ^ (lrow & 15)) * 4 + (lcol & 3)] = v;
            }
        }
    }
    SCHED0;
    asm volatile("s_waitcnt lgkmcnt(0)" ::: "memory");
    SCHED0;

    // read-back: 8 passes; lane handles row (pass*8 + lane>>3), cols (lane&7)*8..+7
    const int rloc = lane >> 3;
    const int cloc = (lane & 7) * 8;
    #pragma unroll
    for (int pass = 0; pass < 8; ++pass) {
        const int lrow = pass * 8 + rloc;                 // 0..63
        const int grow = m0 + wr * 64 + lrow;
        const size_t gbase = (size_t)grow * D_DIM + (n0 + wc * 64 + cloc);
        const int c0 = cloc >> 2;                         // even chunk index
        float4 v0 = *reinterpret_cast<const float4*>(&cwave[lrow * 64 + ((c0    ) ^ (lrow & 15)) * 4]);
        float4 v1 = *reinterpret_cast<const float4*>(&cwave[lrow * 64 + ((c0 + 1) ^ (lrow & 15)) * 4]);
        float vv[8] = {v0.x, v0.y, v0.z, v0.w, v1.x, v1.y, v1.z, v1.w};
        if (MODE != 0) {
            u16x8 rh = *reinterpret_cast<const u16x8*>(&RH[gbase]);
            u16x8 rl2 = *reinterpret_cast<const u16x8*>(&RL[gbase]);
            #pragma unroll
            for (int k = 0; k < 8; ++k)
                vv[k] += bfbits2f(rh[k]) + bfbits2f(rl2[k]);
        }
        if (MODE == 2) {
            *reinterpret_cast<float4*>(&Of[gbase])     = make_float4(vv[0], vv[1], vv[2], vv[3]);
            *reinterpret_cast<float4*>(&Of[gbase + 4]) = make_float4(vv[4], vv[5], vv[6], vv[7]);
        } else {
            u16x8 ho, lo2;
            #pragma unroll
            for (int k = 0; k < 8; ++k) {
                unsigned short h, l2;
                split_bf(vv[k], h, l2);
                ho[k] = h; lo2[k] = l2;
            }
            *reinterpret_cast<u16x8*>(&OH[gbase]) = ho;
            *reinterpret_cast<u16x8*>(&OL[gbase]) = lo2;
        }
    }
}

// ---------------------------------------------------------------------------
// LayerNorm on hi/lo pair. One block per row, 256 threads x 4 elems.
// ---------------------------------------------------------------------------
__global__ __launch_bounds__(256)
void ln_pair(const bf16* __restrict__ XH, const bf16* __restrict__ XL,
             bf16* __restrict__ YH, bf16* __restrict__ YL,
             const float* __restrict__ gamma, const float* __restrict__ beta)
{
    const int row = blockIdx.x;
    const int tid = threadIdx.x;
    const int lane = tid & 63;
    const int wave = tid >> 6;

    ushort4 uh = reinterpret_cast<const ushort4*>(XH + (size_t)row * D_DIM)[tid];
    ushort4 ul = reinterpret_cast<const ushort4*>(XL + (size_t)row * D_DIM)[tid];
    float v0 = bfbits2f(uh.x) + bfbits2f(ul.x);
    float v1 = bfbits2f(uh.y) + bfbits2f(ul.y);
    float v2 = bfbits2f(uh.z) + bfbits2f(ul.z);
    float v3 = bfbits2f(uh.w) + bfbits2f(ul.w);
    float s  = v0 + v1 + v2 + v3;
    float ss = v0 * v0 + v1 * v1 + v2 * v2 + v3 * v3;
    #pragma unroll
    for (int off = 32; off >= 1; off >>= 1) {
        s  += __shfl_xor(s, off, 64);
        ss += __shfl_xor(ss, off, 64);
    }
    __shared__ float red[8];
    if (lane == 0) { red[wave] = s; red[4 + wave] = ss; }
    __syncthreads();
    float S  = red[0] + red[1] + red[2] + red[3];
    float SS = red[4] + red[5] + red[6] + red[7];
    const float mean = S * (1.0f / D_DIM);
    const float var  = SS * (1.0f / D_DIM) - mean * mean;
    const float inv  = rsqrtf(var + 1e-5f);

    const int c0 = tid * 4;
    float y0 = (v0 - mean) * inv * gamma[c0 + 0] + beta[c0 + 0];
    float y1 = (v1 - mean) * inv * gamma[c0 + 1] + beta[c0 + 1];
    float y2 = (v2 - mean) * inv * gamma[c0 + 2] + beta[c0 + 2];
    float y3 = (v3 - mean) * inv * gamma[c0 + 3] + beta[c0 + 3];
    ushort4 oh, ol;
    split_bf(y0, oh.x, ol.x); split_bf(y1, oh.y, ol.y);
    split_bf(y2, oh.z, ol.z); split_bf(y3, oh.w, ol.w);
    reinterpret_cast<ushort4*>(YH + (size_t)row * D_DIM)[tid] = oh;
    reinterpret_cast<ushort4*>(YL + (size_t)row * D_DIM)[tid] = ol;
}

// ---------------------------------------------------------------------------
extern "C" void kernel_launch(void* const* d_in, const int* in_sizes, int n_in,
                              void* d_out, int out_size, void* d_ws, size_t ws_size,
                              hipStream_t stream)
{
    const float* x      = (const float*)d_in[0];
    const int*   wq     = (const int*)d_in[1];
    const float* scales = (const float*)d_in[2];
    const float* bias   = (const float*)d_in[3];
    const float* lora_a = (const float*)d_in[4];
    const float* lora_b = (const float*)d_in[5];
    const float* ln_g   = (const float*)d_in[6];
    const float* ln_b   = (const float*)d_in[7];
    float* out = (float*)d_out;

    char* ws = (char*)d_ws;
    const size_t W_ELEMS = (size_t)NLAYER * D_DIM * D_DIM;
    const size_t H_ELEMS = (size_t)B_ROWS * D_DIM;
    bf16* WHp = (bf16*)ws;
    bf16* WLp = WHp + W_ELEMS;
    bf16* HAh = WLp + W_ELEMS;
    bf16* HAl = HAh + H_ELEMS;
    bf16* HBh = HAl + H_ELEMS;
    bf16* HBl = HBh + H_ELEMS;
    // third activation pair lives in d_out (dead before final write)
    bf16* HCh = (bf16*)d_out;
    bf16* HCl = HCh + H_ELEMS;

    build_weff<<<dim3(NLAYER * 128), dim3(256), 0, stream>>>(wq, scales, lora_a, lora_b, WHp, WLp);
    cast_split<<<dim3((B_ROWS * D_DIM) / (256 * 4)), dim3(256), 0, stream>>>(x, HAh, HAl);

    dim3 ggrid(1024);  // 8 n-tiles x 128 m-tiles, swizzled in-kernel
    for (int j = 0; j < 6; ++j) {
        const int l0 = 3 * j;
        const bf16* WH0 = WHp + (size_t)l0 * D_DIM * D_DIM;
        const bf16* WL0 = WLp + (size_t)l0 * D_DIM * D_DIM;
        const bf16* WH1 = WHp + (size_t)(l0 + 1) * D_DIM * D_DIM;
        const bf16* WL1 = WLp + (size_t)(l0 + 1) * D_DIM * D_DIM;
        const bf16* WH2 = WHp + (size_t)(l0 + 2) * D_DIM * D_DIM;
        const bf16* WL2 = WLp + (size_t)(l0 + 2) * D_DIM * D_DIM;
        const float* b0 = bias + (size_t)l0 * D_DIM;
        const float* b1 = bias + (size_t)(l0 + 1) * D_DIM;
        const float* b2 = bias + (size_t)(l0 + 2) * D_DIM;
        if (j < 5) {
            qgemm3<0><<<ggrid, 256, 0, stream>>>(HAh, HAl, WH0, WL0, b0, nullptr, nullptr, HBh, HBl, nullptr);
            qgemm3<0><<<ggrid, 256, 0, stream>>>(HBh, HBl, WH1, WL1, b1, nullptr, nullptr, HCh, HCl, nullptr);
            qgemm3<1><<<ggrid, 256, 0, stream>>>(HCh, HCl, WH2, WL2, b2, HAh, HAl, HBh, HBl, nullptr);
            ln_pair<<<dim3(B_ROWS), dim3(256), 0, stream>>>(HBh, HBl, HAh, HAl,
                                                            ln_g + (size_t)j * D_DIM, ln_b + (size_t)j * D_DIM);
        } else {
            qgemm3<0><<<ggrid, 256, 0, stream>>>(HAh, HAl, WH0, WL0, b0, nullptr, nullptr, HCh, HCl, nullptr);
            qgemm3<0><<<ggrid, 256, 0, stream>>>(HCh, HCl, WH1, WL1, b1, nullptr, nullptr, HBh, HBl, nullptr);
            qgemm3<2><<<ggrid, 256, 0, stream>>>(HBh, HBl, WH2, WL2, b2, HAh, HAl, nullptr, nullptr, out);
        }
    }
}

// Round 8
// 1960.206 us; speedup vs baseline: 1.4974x; 1.4974x over previous
//
#include <hip/hip_runtime.h>
#include <hip/hip_bf16.h>
#include <stdint.h>

using bf16 = __hip_bfloat16;
typedef __attribute__((ext_vector_type(8))) short bf16x8;
typedef __attribute__((ext_vector_type(8))) unsigned short u16x8;
typedef __attribute__((ext_vector_type(4))) float f32x4;

#define B_ROWS 16384
#define D_DIM  1024
#define NLAYER 18

__device__ inline void gload_lds16(const bf16* g, bf16* l) {
    __builtin_amdgcn_global_load_lds(
        (const __attribute__((address_space(1))) void*)g,
        (__attribute__((address_space(3))) void*)l, 16, 0, 0);
}

__device__ inline unsigned short f2bf_bits(float f) {
    bf16 h = __float2bfloat16(f);
    return *reinterpret_cast<unsigned short*>(&h);
}
__device__ inline float bfbits2f(unsigned short u) {
    unsigned int x = ((unsigned int)u) << 16;
    return __uint_as_float(x);
}
// double-bf16 split: v ~= hi + lo with rel err ~2^-18
__device__ inline void split_bf(float v, unsigned short& hi, unsigned short& lo) {
    hi = f2bf_bits(v);
    float hf = bfbits2f(hi);
    lo = f2bf_bits(v - hf);
}

// ---------------------------------------------------------------------------
// Weff[l][o][i] = (wq-8)*scale + sum_r lora_b[l][o][r]*lora_a[l][r][i]
// stored as hi/lo bf16 pair. One block per (l, 8-row group): lora_a float4
// reads amortized over 8 output rows (proven in round 7: ~35us vs 131us).
// ---------------------------------------------------------------------------
__global__ __launch_bounds__(256)
void build_weff(const int* __restrict__ wq, const float* __restrict__ scales,
                const float* __restrict__ lora_a, const float* __restrict__ lora_b,
                bf16* __restrict__ weff_h, bf16* __restrict__ weff_l)
{
    const int bb = blockIdx.x;           // 18 * 128
    const int l  = bb >> 7;
    const int o0 = (bb & 127) * 8;
    __shared__ float bsh[8][32];
    {
        const int oo = threadIdx.x >> 5, rr = threadIdx.x & 31;
        bsh[oo][rr] = lora_b[((size_t)l * 1024 + o0 + oo) * 32 + rr];
    }
    __syncthreads();

    const float* abase = lora_a + (size_t)l * 32 * 1024;
    const int i0 = threadIdx.x * 4;      // 256 threads x 4 = 1024 i's
    float acc[8][4] = {};
    #pragma unroll 4
    for (int r = 0; r < 32; ++r) {
        float4 av = *reinterpret_cast<const float4*>(abase + (size_t)r * 1024 + i0);
        #pragma unroll
        for (int o = 0; o < 8; ++o) {
            const float br = bsh[o][r];
            acc[o][0] += br * av.x; acc[o][1] += br * av.y;
            acc[o][2] += br * av.z; acc[o][3] += br * av.w;
        }
    }
    #pragma unroll
    for (int o = 0; o < 8; ++o) {
        const size_t row = (size_t)l * 1024 + o0 + o;
        int4 q = *reinterpret_cast<const int4*>(wq + row * 1024 + i0);
        const float sc = scales[row * 64 + (i0 >> 4)];
        float w0 = (q.x - 8) * sc + acc[o][0];
        float w1 = (q.y - 8) * sc + acc[o][1];
        float w2 = (q.z - 8) * sc + acc[o][2];
        float w3 = (q.w - 8) * sc + acc[o][3];
        ushort4 uh, ul;
        split_bf(w0, uh.x, ul.x); split_bf(w1, uh.y, ul.y);
        split_bf(w2, uh.z, ul.z); split_bf(w3, uh.w, ul.w);
        *reinterpret_cast<ushort4*>(weff_h + row * 1024 + i0) = uh;
        *reinterpret_cast<ushort4*>(weff_l + row * 1024 + i0) = ul;
    }
}

// ---------------------------------------------------------------------------
// x f32 -> hi/lo bf16 pair
// ---------------------------------------------------------------------------
__global__ __launch_bounds__(256)
void cast_split(const float* __restrict__ x, bf16* __restrict__ yh, bf16* __restrict__ yl)
{
    size_t i = ((size_t)blockIdx.x * 256 + threadIdx.x) * 4;
    float4 v = *reinterpret_cast<const float4*>(x + i);
    ushort4 uh, ul;
    split_bf(v.x, uh.x, ul.x); split_bf(v.y, uh.y, ul.y);
    split_bf(v.z, uh.z, ul.z); split_bf(v.w, uh.w, ul.w);
    *reinterpret_cast<ushort4*>(yh + i) = uh;
    *reinterpret_cast<ushort4*>(yl + i) = ul;
}

// ---------------------------------------------------------------------------
// GEMM, double-bf16 operands, 3 MFMA products: acc += Ah*Wh + Ah*Wl + Al*Wh
// 128x128 tile, BK=32, 4 waves, 2-deep counted-vmcnt pipeline (round-6
// structure, proven ~99us). NEW: MFMA cluster split in half — m=0,1 hoisted
// before the lgkmcnt(0)/bar2/stage point so the compiler's counted lgkm
// waits overlap ds_read latency with MFMA issue within each wave.
// MODE 0: relu -> pair out;  MODE 1: +res -> pair out;  MODE 2: +res -> f32
// ---------------------------------------------------------------------------
#define TILE_E 4096            // elems per LDS tile (128 rows x 32)
#define SET_E  (4 * TILE_E)    // elems per buffer set (ASH,ASL,BSH,BSL)

#define SCHED0 __builtin_amdgcn_sched_barrier(0)

template<int MODE>
__global__ __launch_bounds__(256)
void qgemm3(const bf16* __restrict__ AH, const bf16* __restrict__ AL,
            const bf16* __restrict__ WH, const bf16* __restrict__ WL,
            const float* __restrict__ bias,
            const bf16* __restrict__ RH, const bf16* __restrict__ RL,
            bf16* __restrict__ OH, bf16* __restrict__ OL,
            float* __restrict__ Of)
{
    __shared__ bf16 smem[2 * SET_E];   // 64 KiB

    // T1: chunked XCD swizzle. nwg = 1024 (8 n-tiles fast, 128 m-tiles).
    const int b  = blockIdx.x;
    const int sb = ((b & 7) << 7) | (b >> 3);
    const int n0 = (sb & 7) * 128;
    const int m0 = (sb >> 3) * 128;

    const int tid  = threadIdx.x;
    const int wave = tid >> 6;
    const int lane = tid & 63;
    const int wr = wave >> 1, wc = wave & 1;

    const int rl = lane >> 2;          // staging: row within 16-row segment
    const int ps = lane & 3;           // staging: phys 16B slot
    const int fr = lane & 15;          // fragment row
    const int fq = lane >> 4;          // fragment k-chunk (16B unit)

    f32x4 acc[4][4] = {};

    // staging: per wave 2 segments x 4 tiles = 8 global_load_lds (vmcnt +8)
    auto stage = [&](int buf, int k0) {
        bf16* base = smem + buf * SET_E;
        #pragma unroll
        for (int t = 0; t < 2; ++t) {
            int s = wave * 2 + t;                   // segment 0..7 (wave-uniform)
            int r = s * 16 + rl;                    // tile row
            int q = ps ^ (r & 3) ^ ((r >> 2) & 3);  // pre-swizzled global chunk
            size_t ga = (size_t)(m0 + r) * D_DIM + k0 + q * 8;
            size_t gb = (size_t)(n0 + r) * D_DIM + k0 + q * 8;
            bf16* dst = base + s * 512;             // wave-uniform; HW adds lane*16B
            gload_lds16(AH + ga, dst);
            gload_lds16(AL + ga, dst + TILE_E);
            gload_lds16(WH + gb, dst + 2 * TILE_E);
            gload_lds16(WL + gb, dst + 3 * TILE_E);
        }
    };

    // ---- prologue: 2-deep prefetch (16 loads in flight per wave)
    stage(0, 0);
    stage(1, 32);

    int cur = 0;
    #pragma unroll 1
    for (int kt = 0; kt < 32; ++kt) {
        // wait only for tile kt's 8 loads; tile kt+1's stay in flight
        SCHED0;
        if (kt <= 30) asm volatile("s_waitcnt vmcnt(8)" ::: "memory");
        else          asm volatile("s_waitcnt vmcnt(0)" ::: "memory");
        SCHED0;
        __builtin_amdgcn_s_barrier();        // tile kt resident for all waves

        const bf16* tb = smem + cur * SET_E;
        bf16x8 ah[4], al[4], bh[4], bl[4];
        #pragma unroll
        for (int n = 0; n < 4; ++n) {
            int R = wc * 64 + n * 16 + fr;
            int p = fq ^ (R & 3) ^ ((R >> 2) & 3);
            int off = R * 32 + p * 8;
            bh[n] = *reinterpret_cast<const bf16x8*>(tb + 2 * TILE_E + off);
            bl[n] = *reinterpret_cast<const bf16x8*>(tb + 3 * TILE_E + off);
        }
        #pragma unroll
        for (int m = 0; m < 4; ++m) {
            int R = wr * 64 + m * 16 + fr;
            int p = fq ^ (R & 3) ^ ((R >> 2) & 3);
            int off = R * 32 + p * 8;
            ah[m] = *reinterpret_cast<const bf16x8*>(tb + off);
            al[m] = *reinterpret_cast<const bf16x8*>(tb + TILE_E + off);
        }

        // first half of MFMAs overlaps the ds_read drain (compiler inserts
        // its own counted lgkmcnt for the operands it needs)
        __builtin_amdgcn_s_setprio(1);
        #pragma unroll
        for (int m = 0; m < 2; ++m)
            #pragma unroll
            for (int n = 0; n < 4; ++n) {
                acc[m][n] = __builtin_amdgcn_mfma_f32_16x16x32_bf16(ah[m], bh[n], acc[m][n], 0, 0, 0);
                acc[m][n] = __builtin_amdgcn_mfma_f32_16x16x32_bf16(ah[m], bl[n], acc[m][n], 0, 0, 0);
                acc[m][n] = __builtin_amdgcn_mfma_f32_16x16x32_bf16(al[m], bh[n], acc[m][n], 0, 0, 0);
            }
        __builtin_amdgcn_s_setprio(0);

        // all reads of buf[cur] retired before anyone overwrites it
        SCHED0;
        asm volatile("s_waitcnt lgkmcnt(0)" ::: "memory");
        SCHED0;
        __builtin_amdgcn_s_barrier();

        if (kt <= 29)
            stage(cur, (kt + 2) * 32);       // overwrite just-consumed buffer

        __builtin_amdgcn_s_setprio(1);
        #pragma unroll
        for (int m = 2; m < 4; ++m)
            #pragma unroll
            for (int n = 0; n < 4; ++n) {
                acc[m][n] = __builtin_amdgcn_mfma_f32_16x16x32_bf16(ah[m], bh[n], acc[m][n], 0, 0, 0);
                acc[m][n] = __builtin_amdgcn_mfma_f32_16x16x32_bf16(ah[m], bl[n], acc[m][n], 0, 0, 0);
                acc[m][n] = __builtin_amdgcn_mfma_f32_16x16x32_bf16(al[m], bh[n], acc[m][n], 0, 0, 0);
            }
        __builtin_amdgcn_s_setprio(0);
        cur ^= 1;
    }

    // ---- Epilogue via LDS transpose (wave-private 16 KiB f32 regions).
    // C/D layout: col = lane&15 (=fr), row = (lane>>4)*4 + j.
    const int crow4 = (lane >> 4) * 4;
    float* cwave = reinterpret_cast<float*>(smem) + wave * 4096;

    #pragma unroll
    for (int n = 0; n < 4; ++n) {
        const float bv = bias[n0 + wc * 64 + n * 16 + fr];
        const int lcol = n * 16 + fr;                     // local col 0..63
        const int chunk = lcol >> 2;
        #pragma unroll
        for (int m = 0; m < 4; ++m) {
            #pragma unroll
            for (int j = 0; j < 4; ++j) {
                const int lrow = m * 16 + crow4 + j;      // local row 0..63
                float v = acc[m][n][j] + bv;
                if (MODE == 0) v = v > 0.f ? v : 0.f;
                cwave[lrow * 64 + (chunk ^ (lrow & 15)) * 4 + (lcol & 3)] = v;
            }
        }
    }
    SCHED0;
    asm volatile("s_waitcnt lgkmcnt(0)" ::: "memory");
    SCHED0;

    // read-back: 8 passes; lane handles row (pass*8 + lane>>3), cols (lane&7)*8..+7
    const int rloc = lane >> 3;
    const int cloc = (lane & 7) * 8;
    #pragma unroll
    for (int pass = 0; pass < 8; ++pass) {
        const int lrow = pass * 8 + rloc;                 // 0..63
        const int grow = m0 + wr * 64 + lrow;
        const size_t gbase = (size_t)grow * D_DIM + (n0 + wc * 64 + cloc);
        const int c0 = cloc >> 2;                         // even chunk index
        float4 v0 = *reinterpret_cast<const float4*>(&cwave[lrow * 64 + ((c0    ) ^ (lrow & 15)) * 4]);
        float4 v1 = *reinterpret_cast<const float4*>(&cwave[lrow * 64 + ((c0 + 1) ^ (lrow & 15)) * 4]);
        float vv[8] = {v0.x, v0.y, v0.z, v0.w, v1.x, v1.y, v1.z, v1.w};
        if (MODE != 0) {
            u16x8 rh = *reinterpret_cast<const u16x8*>(&RH[gbase]);
            u16x8 rl2 = *reinterpret_cast<const u16x8*>(&RL[gbase]);
            #pragma unroll
            for (int k = 0; k < 8; ++k)
                vv[k] += bfbits2f(rh[k]) + bfbits2f(rl2[k]);
        }
        if (MODE == 2) {
            *reinterpret_cast<float4*>(&Of[gbase])     = make_float4(vv[0], vv[1], vv[2], vv[3]);
            *reinterpret_cast<float4*>(&Of[gbase + 4]) = make_float4(vv[4], vv[5], vv[6], vv[7]);
        } else {
            u16x8 ho, lo2;
            #pragma unroll
            for (int k = 0; k < 8; ++k) {
                unsigned short h, l2;
                split_bf(vv[k], h, l2);
                ho[k] = h; lo2[k] = l2;
            }
            *reinterpret_cast<u16x8*>(&OH[gbase]) = ho;
            *reinterpret_cast<u16x8*>(&OL[gbase]) = lo2;
        }
    }
}

// ---------------------------------------------------------------------------
// LayerNorm on hi/lo pair. One block per row, 256 threads x 4 elems.
// ---------------------------------------------------------------------------
__global__ __launch_bounds__(256)
void ln_pair(const bf16* __restrict__ XH, const bf16* __restrict__ XL,
             bf16* __restrict__ YH, bf16* __restrict__ YL,
             const float* __restrict__ gamma, const float* __restrict__ beta)
{
    const int row = blockIdx.x;
    const int tid = threadIdx.x;
    const int lane = tid & 63;
    const int wave = tid >> 6;

    ushort4 uh = reinterpret_cast<const ushort4*>(XH + (size_t)row * D_DIM)[tid];
    ushort4 ul = reinterpret_cast<const ushort4*>(XL + (size_t)row * D_DIM)[tid];
    float v0 = bfbits2f(uh.x) + bfbits2f(ul.x);
    float v1 = bfbits2f(uh.y) + bfbits2f(ul.y);
    float v2 = bfbits2f(uh.z) + bfbits2f(ul.z);
    float v3 = bfbits2f(uh.w) + bfbits2f(ul.w);
    float s  = v0 + v1 + v2 + v3;
    float ss = v0 * v0 + v1 * v1 + v2 * v2 + v3 * v3;
    #pragma unroll
    for (int off = 32; off >= 1; off >>= 1) {
        s  += __shfl_xor(s, off, 64);
        ss += __shfl_xor(ss, off, 64);
    }
    __shared__ float red[8];
    if (lane == 0) { red[wave] = s; red[4 + wave] = ss; }
    __syncthreads();
    float S  = red[0] + red[1] + red[2] + red[3];
    float SS = red[4] + red[5] + red[6] + red[7];
    const float mean = S * (1.0f / D_DIM);
    const float var  = SS * (1.0f / D_DIM) - mean * mean;
    const float inv  = rsqrtf(var + 1e-5f);

    const int c0 = tid * 4;
    float y0 = (v0 - mean) * inv * gamma[c0 + 0] + beta[c0 + 0];
    float y1 = (v1 - mean) * inv * gamma[c0 + 1] + beta[c0 + 1];
    float y2 = (v2 - mean) * inv * gamma[c0 + 2] + beta[c0 + 2];
    float y3 = (v3 - mean) * inv * gamma[c0 + 3] + beta[c0 + 3];
    ushort4 oh, ol;
    split_bf(y0, oh.x, ol.x); split_bf(y1, oh.y, ol.y);
    split_bf(y2, oh.z, ol.z); split_bf(y3, oh.w, ol.w);
    reinterpret_cast<ushort4*>(YH + (size_t)row * D_DIM)[tid] = oh;
    reinterpret_cast<ushort4*>(YL + (size_t)row * D_DIM)[tid] = ol;
}

// ---------------------------------------------------------------------------
extern "C" void kernel_launch(void* const* d_in, const int* in_sizes, int n_in,
                              void* d_out, int out_size, void* d_ws, size_t ws_size,
                              hipStream_t stream)
{
    const float* x      = (const float*)d_in[0];
    const int*   wq     = (const int*)d_in[1];
    const float* scales = (const float*)d_in[2];
    const float* bias   = (const float*)d_in[3];
    const float* lora_a = (const float*)d_in[4];
    const float* lora_b = (const float*)d_in[5];
    const float* ln_g   = (const float*)d_in[6];
    const float* ln_b   = (const float*)d_in[7];
    float* out = (float*)d_out;

    char* ws = (char*)d_ws;
    const size_t W_ELEMS = (size_t)NLAYER * D_DIM * D_DIM;
    const size_t H_ELEMS = (size_t)B_ROWS * D_DIM;
    bf16* WHp = (bf16*)ws;
    bf16* WLp = WHp + W_ELEMS;
    bf16* HAh = WLp + W_ELEMS;
    bf16* HAl = HAh + H_ELEMS;
    bf16* HBh = HAl + H_ELEMS;
    bf16* HBl = HBh + H_ELEMS;
    // third activation pair lives in d_out (dead before final write)
    bf16* HCh = (bf16*)d_out;
    bf16* HCl = HCh + H_ELEMS;

    build_weff<<<dim3(NLAYER * 128), dim3(256), 0, stream>>>(wq, scales, lora_a, lora_b, WHp, WLp);
    cast_split<<<dim3((B_ROWS * D_DIM) / (256 * 4)), dim3(256), 0, stream>>>(x, HAh, HAl);

    dim3 ggrid(1024);  // 8 n-tiles x 128 m-tiles, swizzled in-kernel
    for (int j = 0; j < 6; ++j) {
        const int l0 = 3 * j;
        const bf16* WH0 = WHp + (size_t)l0 * D_DIM * D_DIM;
        const bf16* WL0 = WLp + (size_t)l0 * D_DIM * D_DIM;
        const bf16* WH1 = WHp + (size_t)(l0 + 1) * D_DIM * D_DIM;
        const bf16* WL1 = WLp + (size_t)(l0 + 1) * D_DIM * D_DIM;
        const bf16* WH2 = WHp + (size_t)(l0 + 2) * D_DIM * D_DIM;
        const bf16* WL2 = WLp + (size_t)(l0 + 2) * D_DIM * D_DIM;
        const float* b0 = bias + (size_t)l0 * D_DIM;
        const float* b1 = bias + (size_t)(l0 + 1) * D_DIM;
        const float* b2 = bias + (size_t)(l0 + 2) * D_DIM;
        if (j < 5) {
            qgemm3<0><<<ggrid, 256, 0, stream>>>(HAh, HAl, WH0, WL0, b0, nullptr, nullptr, HBh, HBl, nullptr);
            qgemm3<0><<<ggrid, 256, 0, stream>>>(HBh, HBl, WH1, WL1, b1, nullptr, nullptr, HCh, HCl, nullptr);
            qgemm3<1><<<ggrid, 256, 0, stream>>>(HCh, HCl, WH2, WL2, b2, HAh, HAl, HBh, HBl, nullptr);
            ln_pair<<<dim3(B_ROWS), dim3(256), 0, stream>>>(HBh, HBl, HAh, HAl,
                                                            ln_g + (size_t)j * D_DIM, ln_b + (size_t)j * D_DIM);
        } else {
            qgemm3<0><<<ggrid, 256, 0, stream>>>(HAh, HAl, WH0, WL0, b0, nullptr, nullptr, HCh, HCl, nullptr);
            qgemm3<0><<<ggrid, 256, 0, stream>>>(HCh, HCl, WH1, WL1, b1, nullptr, nullptr, HBh, HBl, nullptr);
            qgemm3<2><<<ggrid, 256, 0, stream>>>(HBh, HBl, WH2, WL2, b2, HAh, HAl, nullptr, nullptr, out);
        }
    }
}

// Round 9
// 1837.894 us; speedup vs baseline: 1.5971x; 1.0666x over previous
//
#include <hip/hip_runtime.h>
#include <hip/hip_bf16.h>
#include <stdint.h>

using bf16 = __hip_bfloat16;
typedef __attribute__((ext_vector_type(8))) short bf16x8;
typedef __attribute__((ext_vector_type(8))) unsigned short u16x8;
typedef __attribute__((ext_vector_type(4))) float f32x4;

#define B_ROWS 16384
#define D_DIM  1024
#define NLAYER 18

__device__ inline void gload_lds16(const bf16* g, bf16* l) {
    __builtin_amdgcn_global_load_lds(
        (const __attribute__((address_space(1))) void*)g,
        (__attribute__((address_space(3))) void*)l, 16, 0, 0);
}

__device__ inline unsigned short f2bf_bits(float f) {
    bf16 h = __float2bfloat16(f);
    return *reinterpret_cast<unsigned short*>(&h);
}
__device__ inline float bfbits2f(unsigned short u) {
    unsigned int x = ((unsigned int)u) << 16;
    return __uint_as_float(x);
}
// double-bf16 split: v ~= hi + lo with rel err ~2^-18
__device__ inline void split_bf(float v, unsigned short& hi, unsigned short& lo) {
    hi = f2bf_bits(v);
    float hf = bfbits2f(hi);
    lo = f2bf_bits(v - hf);
}

// ---------------------------------------------------------------------------
// Weff[l][o][i] = (wq-8)*scale + sum_r lora_b[l][o][r]*lora_a[l][r][i]
// stored as hi/lo bf16 pair. One block per (l, 8-row group) (proven r7).
// ---------------------------------------------------------------------------
__global__ __launch_bounds__(256)
void build_weff(const int* __restrict__ wq, const float* __restrict__ scales,
                const float* __restrict__ lora_a, const float* __restrict__ lora_b,
                bf16* __restrict__ weff_h, bf16* __restrict__ weff_l)
{
    const int bb = blockIdx.x;           // 18 * 128
    const int l  = bb >> 7;
    const int o0 = (bb & 127) * 8;
    __shared__ float bsh[8][32];
    {
        const int oo = threadIdx.x >> 5, rr = threadIdx.x & 31;
        bsh[oo][rr] = lora_b[((size_t)l * 1024 + o0 + oo) * 32 + rr];
    }
    __syncthreads();

    const float* abase = lora_a + (size_t)l * 32 * 1024;
    const int i0 = threadIdx.x * 4;      // 256 threads x 4 = 1024 i's
    float acc[8][4] = {};
    #pragma unroll 4
    for (int r = 0; r < 32; ++r) {
        float4 av = *reinterpret_cast<const float4*>(abase + (size_t)r * 1024 + i0);
        #pragma unroll
        for (int o = 0; o < 8; ++o) {
            const float br = bsh[o][r];
            acc[o][0] += br * av.x; acc[o][1] += br * av.y;
            acc[o][2] += br * av.z; acc[o][3] += br * av.w;
        }
    }
    #pragma unroll
    for (int o = 0; o < 8; ++o) {
        const size_t row = (size_t)l * 1024 + o0 + o;
        int4 q = *reinterpret_cast<const int4*>(wq + row * 1024 + i0);
        const float sc = scales[row * 64 + (i0 >> 4)];
        float w0 = (q.x - 8) * sc + acc[o][0];
        float w1 = (q.y - 8) * sc + acc[o][1];
        float w2 = (q.z - 8) * sc + acc[o][2];
        float w3 = (q.w - 8) * sc + acc[o][3];
        ushort4 uh, ul;
        split_bf(w0, uh.x, ul.x); split_bf(w1, uh.y, ul.y);
        split_bf(w2, uh.z, ul.z); split_bf(w3, uh.w, ul.w);
        *reinterpret_cast<ushort4*>(weff_h + row * 1024 + i0) = uh;
        *reinterpret_cast<ushort4*>(weff_l + row * 1024 + i0) = ul;
    }
}

// ---------------------------------------------------------------------------
// x f32 -> hi/lo bf16 pair
// ---------------------------------------------------------------------------
__global__ __launch_bounds__(256)
void cast_split(const float* __restrict__ x, bf16* __restrict__ yh, bf16* __restrict__ yl)
{
    size_t i = ((size_t)blockIdx.x * 256 + threadIdx.x) * 4;
    float4 v = *reinterpret_cast<const float4*>(x + i);
    ushort4 uh, ul;
    split_bf(v.x, uh.x, ul.x); split_bf(v.y, uh.y, ul.y);
    split_bf(v.z, uh.z, ul.z); split_bf(v.w, uh.w, ul.w);
    *reinterpret_cast<ushort4*>(yh + i) = uh;
    *reinterpret_cast<ushort4*>(yl + i) = ul;
}

// ---------------------------------------------------------------------------
// GEMM, double-bf16 operands, 3 MFMA products: acc += Ah*Wh + Ah*Wl + Al*Wh
// 256x256 tile, BK=32, 8 waves (2M x 4N, per-wave 128x64): 24 ds_read_b128
// per 96 MFMA (-25% LDS bytes/FLOP vs 128^2 — the r8-measured bottleneck).
// Same proven 2-deep counted-vmcnt schedule (8 loads/wave/K-step, vmcnt(8)),
// r8's MFMA split around the drain/stage point, wide 2-pass LDS-transpose
// epilogue (sector-complete stores — fixes r5's write-amplification).
// MODE 0: relu -> pair out;  MODE 1: +res -> pair out;  MODE 2: +res -> f32
// ---------------------------------------------------------------------------
#define TILE_E 8192            // elems per LDS tensor tile (256 rows x 32)
#define SET_E  (4 * TILE_E)    // Ah, Al, Wh, Wl

#define SCHED0 __builtin_amdgcn_sched_barrier(0)

template<int MODE>
__global__ __launch_bounds__(512)
void qgemm3(const bf16* __restrict__ AH, const bf16* __restrict__ AL,
            const bf16* __restrict__ WH, const bf16* __restrict__ WL,
            const float* __restrict__ bias,
            const bf16* __restrict__ RH, const bf16* __restrict__ RL,
            bf16* __restrict__ OH, bf16* __restrict__ OL,
            float* __restrict__ Of)
{
    __shared__ bf16 smem[2 * SET_E];   // 128 KiB

    // T1: chunked XCD swizzle, nwg = 256 (64 m-tiles x 4 n-tiles), 256%8==0.
    const int b  = blockIdx.x;
    const int sb = ((b & 7) << 5) | (b >> 3);
    const int n0 = (sb & 3) * 256;
    const int m0 = (sb >> 2) * 256;

    const int tid  = threadIdx.x;
    const int wave = tid >> 6;
    const int lane = tid & 63;
    const int wr = wave >> 2;          // 0..1  M half (128 rows)
    const int wc = wave & 3;           // 0..3  N strip (64 cols)

    const int rl = lane >> 2;          // staging: row within 16-row segment
    const int ps = lane & 3;           // staging: phys 16B slot
    const int fr = lane & 15;          // fragment row
    const int fq = lane >> 4;          // fragment k-chunk (16B unit)

    f32x4 acc[8][4] = {};

    // staging: wave w covers rows [w*32, w*32+32) of both A and W panels:
    // 2 segments x 4 tensors = 8 global_load_lds (vmcnt +8 per wave)
    auto stage = [&](int buf, int k0) {
        bf16* base = smem + buf * SET_E;
        #pragma unroll
        for (int t = 0; t < 2; ++t) {
            int s = wave * 2 + t;                   // segment 0..15 (wave-uniform)
            int r = s * 16 + rl;                    // tile row
            int q = ps ^ (r & 3) ^ ((r >> 2) & 3);  // pre-swizzled global chunk
            size_t ga = (size_t)(m0 + r) * D_DIM + k0 + q * 8;
            size_t gb = (size_t)(n0 + r) * D_DIM + k0 + q * 8;
            bf16* dst = base + s * 512;             // wave-uniform; HW adds lane*16B
            gload_lds16(AH + ga, dst);
            gload_lds16(AL + ga, dst + TILE_E);
            gload_lds16(WH + gb, dst + 2 * TILE_E);
            gload_lds16(WL + gb, dst + 3 * TILE_E);
        }
    };

    // ---- prologue: 2-deep prefetch (16 loads in flight per wave)
    stage(0, 0);
    stage(1, 32);

    #pragma unroll 1
    for (int kt = 0; kt < 32; ++kt) {
        const int cur = kt & 1;
        // wait only for tile kt's 8 loads; tile kt+1's stay in flight
        SCHED0;
        if (kt < 31) asm volatile("s_waitcnt vmcnt(8)" ::: "memory");
        else         asm volatile("s_waitcnt vmcnt(0)" ::: "memory");
        SCHED0;
        __builtin_amdgcn_s_barrier();        // tile kt resident for all waves

        const bf16* tb = smem + cur * SET_E;
        bf16x8 wh[4], wl[4], ah[8], al[8];
        #pragma unroll
        for (int n = 0; n < 4; ++n) {
            int R = wc * 64 + n * 16 + fr;
            int p = fq ^ (R & 3) ^ ((R >> 2) & 3);
            int off = R * 32 + p * 8;
            wh[n] = *reinterpret_cast<const bf16x8*>(tb + 2 * TILE_E + off);
            wl[n] = *reinterpret_cast<const bf16x8*>(tb + 3 * TILE_E + off);
        }
        #pragma unroll
        for (int m = 0; m < 8; ++m) {
            int R = wr * 128 + m * 16 + fr;
            int p = fq ^ (R & 3) ^ ((R >> 2) & 3);
            int off = R * 32 + p * 8;
            ah[m] = *reinterpret_cast<const bf16x8*>(tb + off);
            al[m] = *reinterpret_cast<const bf16x8*>(tb + TILE_E + off);
        }

        // first half (m=0..3) overlaps the ds_read drain
        __builtin_amdgcn_s_setprio(1);
        #pragma unroll
        for (int m = 0; m < 4; ++m)
            #pragma unroll
            for (int n = 0; n < 4; ++n) {
                acc[m][n] = __builtin_amdgcn_mfma_f32_16x16x32_bf16(ah[m], wh[n], acc[m][n], 0, 0, 0);
                acc[m][n] = __builtin_amdgcn_mfma_f32_16x16x32_bf16(ah[m], wl[n], acc[m][n], 0, 0, 0);
                acc[m][n] = __builtin_amdgcn_mfma_f32_16x16x32_bf16(al[m], wh[n], acc[m][n], 0, 0, 0);
            }
        __builtin_amdgcn_s_setprio(0);

        // all reads of buf[cur] retired before anyone overwrites it
        SCHED0;
        asm volatile("s_waitcnt lgkmcnt(0)" ::: "memory");
        SCHED0;
        __builtin_amdgcn_s_barrier();

        if (kt <= 29)
            stage(cur, (kt + 2) * 32);       // overwrite just-consumed buffer

        __builtin_amdgcn_s_setprio(1);
        #pragma unroll
        for (int m = 4; m < 8; ++m)
            #pragma unroll
            for (int n = 0; n < 4; ++n) {
                acc[m][n] = __builtin_amdgcn_mfma_f32_16x16x32_bf16(ah[m], wh[n], acc[m][n], 0, 0, 0);
                acc[m][n] = __builtin_amdgcn_mfma_f32_16x16x32_bf16(ah[m], wl[n], acc[m][n], 0, 0, 0);
                acc[m][n] = __builtin_amdgcn_mfma_f32_16x16x32_bf16(al[m], wh[n], acc[m][n], 0, 0, 0);
            }
        __builtin_amdgcn_s_setprio(0);
    }

    // ---- Epilogue via LDS transpose, 2 half-passes (per-wave 64x64 f32 =
    // 16 KiB x 8 waves = 128 KiB). Wave-private regions; DS ops are in-order
    // per wave, so pass 1's writes can't pass pass 0's reads.
    // C/D layout: col = lane&15 (=fr), row = (lane>>4)*4 + j.
    const int crow4 = (lane >> 4) * 4;
    float* cwave = reinterpret_cast<float*>(smem) + wave * 4096;
    const int rloc = lane >> 3;
    const int cloc = (lane & 7) * 8;

    #pragma unroll
    for (int half = 0; half < 2; ++half) {
        #pragma unroll
        for (int n = 0; n < 4; ++n) {
            const float bv = bias[n0 + wc * 64 + n * 16 + fr];
            const int lcol = n * 16 + fr;                 // local col 0..63
            const int chunk = lcol >> 2;
            #pragma unroll
            for (int mm = 0; mm < 4; ++mm) {
                const int m = half * 4 + mm;
                #pragma unroll
                for (int j = 0; j < 4; ++j) {
                    const int lrow = mm * 16 + crow4 + j; // local row 0..63
                    float v = acc[m][n][j] + bv;
                    if (MODE == 0) v = v > 0.f ? v : 0.f;
                    cwave[lrow * 64 + (chunk ^ (lrow & 15)) * 4 + (lcol & 3)] = v;
                }
            }
        }
        SCHED0;
        asm volatile("s_waitcnt lgkmcnt(0)" ::: "memory");
        SCHED0;

        #pragma unroll
        for (int pass = 0; pass < 8; ++pass) {
            const int lrow = pass * 8 + rloc;             // 0..63
            const int grow = m0 + wr * 128 + half * 64 + lrow;
            const size_t gbase = (size_t)grow * D_DIM + (n0 + wc * 64 + cloc);
            const int c0 = cloc >> 2;
            float4 v0 = *reinterpret_cast<const float4*>(&cwave[lrow * 64 + ((c0    ) ^ (lrow & 15)) * 4]);
            float4 v1 = *reinterpret_cast<const float4*>(&cwave[lrow * 64 + ((c0 + 1) ^ (lrow & 15)) * 4]);
            float vv[8] = {v0.x, v0.y, v0.z, v0.w, v1.x, v1.y, v1.z, v1.w};
            if (MODE != 0) {
                u16x8 rh = *reinterpret_cast<const u16x8*>(&RH[gbase]);
                u16x8 rl2 = *reinterpret_cast<const u16x8*>(&RL[gbase]);
                #pragma unroll
                for (int k = 0; k < 8; ++k)
                    vv[k] += bfbits2f(rh[k]) + bfbits2f(rl2[k]);
            }
            if (MODE == 2) {
                *reinterpret_cast<float4*>(&Of[gbase])     = make_float4(vv[0], vv[1], vv[2], vv[3]);
                *reinterpret_cast<float4*>(&Of[gbase + 4]) = make_float4(vv[4], vv[5], vv[6], vv[7]);
            } else {
                u16x8 ho, lo2;
                #pragma unroll
                for (int k = 0; k < 8; ++k) {
                    unsigned short h, l2;
                    split_bf(vv[k], h, l2);
                    ho[k] = h; lo2[k] = l2;
                }
                *reinterpret_cast<u16x8*>(&OH[gbase]) = ho;
                *reinterpret_cast<u16x8*>(&OL[gbase]) = lo2;
            }
        }
        SCHED0;
        asm volatile("s_waitcnt lgkmcnt(0)" ::: "memory");
        SCHED0;
    }
}

// ---------------------------------------------------------------------------
// LayerNorm on hi/lo pair. One block per row, 256 threads x 4 elems.
// ---------------------------------------------------------------------------
__global__ __launch_bounds__(256)
void ln_pair(const bf16* __restrict__ XH, const bf16* __restrict__ XL,
             bf16* __restrict__ YH, bf16* __restrict__ YL,
             const float* __restrict__ gamma, const float* __restrict__ beta)
{
    const int row = blockIdx.x;
    const int tid = threadIdx.x;
    const int lane = tid & 63;
    const int wave = tid >> 6;

    ushort4 uh = reinterpret_cast<const ushort4*>(XH + (size_t)row * D_DIM)[tid];
    ushort4 ul = reinterpret_cast<const ushort4*>(XL + (size_t)row * D_DIM)[tid];
    float v0 = bfbits2f(uh.x) + bfbits2f(ul.x);
    float v1 = bfbits2f(uh.y) + bfbits2f(ul.y);
    float v2 = bfbits2f(uh.z) + bfbits2f(ul.z);
    float v3 = bfbits2f(uh.w) + bfbits2f(ul.w);
    float s  = v0 + v1 + v2 + v3;
    float ss = v0 * v0 + v1 * v1 + v2 * v2 + v3 * v3;
    #pragma unroll
    for (int off = 32; off >= 1; off >>= 1) {
        s  += __shfl_xor(s, off, 64);
        ss += __shfl_xor(ss, off, 64);
    }
    __shared__ float red[8];
    if (lane == 0) { red[wave] = s; red[4 + wave] = ss; }
    __syncthreads();
    float S  = red[0] + red[1] + red[2] + red[3];
    float SS = red[4] + red[5] + red[6] + red[7];
    const float mean = S * (1.0f / D_DIM);
    const float var  = SS * (1.0f / D_DIM) - mean * mean;
    const float inv  = rsqrtf(var + 1e-5f);

    const int c0 = tid * 4;
    float y0 = (v0 - mean) * inv * gamma[c0 + 0] + beta[c0 + 0];
    float y1 = (v1 - mean) * inv * gamma[c0 + 1] + beta[c0 + 1];
    float y2 = (v2 - mean) * inv * gamma[c0 + 2] + beta[c0 + 2];
    float y3 = (v3 - mean) * inv * gamma[c0 + 3] + beta[c0 + 3];
    ushort4 oh, ol;
    split_bf(y0, oh.x, ol.x); split_bf(y1, oh.y, ol.y);
    split_bf(y2, oh.z, ol.z); split_bf(y3, oh.w, ol.w);
    reinterpret_cast<ushort4*>(YH + (size_t)row * D_DIM)[tid] = oh;
    reinterpret_cast<ushort4*>(YL + (size_t)row * D_DIM)[tid] = ol;
}

// ---------------------------------------------------------------------------
extern "C" void kernel_launch(void* const* d_in, const int* in_sizes, int n_in,
                              void* d_out, int out_size, void* d_ws, size_t ws_size,
                              hipStream_t stream)
{
    const float* x      = (const float*)d_in[0];
    const int*   wq     = (const int*)d_in[1];
    const float* scales = (const float*)d_in[2];
    const float* bias   = (const float*)d_in[3];
    const float* lora_a = (const float*)d_in[4];
    const float* lora_b = (const float*)d_in[5];
    const float* ln_g   = (const float*)d_in[6];
    const float* ln_b   = (const float*)d_in[7];
    float* out = (float*)d_out;

    char* ws = (char*)d_ws;
    const size_t W_ELEMS = (size_t)NLAYER * D_DIM * D_DIM;
    const size_t H_ELEMS = (size_t)B_ROWS * D_DIM;
    bf16* WHp = (bf16*)ws;
    bf16* WLp = WHp + W_ELEMS;
    bf16* HAh = WLp + W_ELEMS;
    bf16* HAl = HAh + H_ELEMS;
    bf16* HBh = HAl + H_ELEMS;
    bf16* HBl = HBh + H_ELEMS;
    // third activation pair lives in d_out (dead before final write)
    bf16* HCh = (bf16*)d_out;
    bf16* HCl = HCh + H_ELEMS;

    build_weff<<<dim3(NLAYER * 128), dim3(256), 0, stream>>>(wq, scales, lora_a, lora_b, WHp, WLp);
    cast_split<<<dim3((B_ROWS * D_DIM) / (256 * 4)), dim3(256), 0, stream>>>(x, HAh, HAl);

    dim3 ggrid(256);  // 64 m-tiles x 4 n-tiles, swizzled in-kernel
    for (int j = 0; j < 6; ++j) {
        const int l0 = 3 * j;
        const bf16* WH0 = WHp + (size_t)l0 * D_DIM * D_DIM;
        const bf16* WL0 = WLp + (size_t)l0 * D_DIM * D_DIM;
        const bf16* WH1 = WHp + (size_t)(l0 + 1) * D_DIM * D_DIM;
        const bf16* WL1 = WLp + (size_t)(l0 + 1) * D_DIM * D_DIM;
        const bf16* WH2 = WHp + (size_t)(l0 + 2) * D_DIM * D_DIM;
        const bf16* WL2 = WLp + (size_t)(l0 + 2) * D_DIM * D_DIM;
        const float* b0 = bias + (size_t)l0 * D_DIM;
        const float* b1 = bias + (size_t)(l0 + 1) * D_DIM;
        const float* b2 = bias + (size_t)(l0 + 2) * D_DIM;
        if (j < 5) {
            qgemm3<0><<<ggrid, 512, 0, stream>>>(HAh, HAl, WH0, WL0, b0, nullptr, nullptr, HBh, HBl, nullptr);
            qgemm3<0><<<ggrid, 512, 0, stream>>>(HBh, HBl, WH1, WL1, b1, nullptr, nullptr, HCh, HCl, nullptr);
            qgemm3<1><<<ggrid, 512, 0, stream>>>(HCh, HCl, WH2, WL2, b2, HAh, HAl, HBh, HBl, nullptr);
            ln_pair<<<dim3(B_ROWS), dim3(256), 0, stream>>>(HBh, HBl, HAh, HAl,
                                                            ln_g + (size_t)j * D_DIM, ln_b + (size_t)j * D_DIM);
        } else {
            qgemm3<0><<<ggrid, 512, 0, stream>>>(HAh, HAl, WH0, WL0, b0, nullptr, nullptr, HCh, HCl, nullptr);
            qgemm3<0><<<ggrid, 512, 0, stream>>>(HCh, HCl, WH1, WL1, b1, nullptr, nullptr, HBh, HBl, nullptr);
            qgemm3<2><<<ggrid, 512, 0, stream>>>(HBh, HBl, WH2, WL2, b2, HAh, HAl, nullptr, nullptr, out);
        }
    }
}

// Round 10
// 1765.918 us; speedup vs baseline: 1.6622x; 1.0408x over previous
//
#include <hip/hip_runtime.h>
#include <hip/hip_bf16.h>
#include <stdint.h>

using bf16 = __hip_bfloat16;
typedef __attribute__((ext_vector_type(8))) short bf16x8;
typedef __attribute__((ext_vector_type(8))) unsigned short u16x8;
typedef __attribute__((ext_vector_type(4))) float f32x4;

#define B_ROWS 16384
#define D_DIM  1024
#define NLAYER 18

__device__ inline void gload_lds16(const bf16* g, bf16* l) {
    __builtin_amdgcn_global_load_lds(
        (const __attribute__((address_space(1))) void*)g,
        (__attribute__((address_space(3))) void*)l, 16, 0, 0);
}

__device__ inline unsigned short f2bf_bits(float f) {
    bf16 h = __float2bfloat16(f);
    return *reinterpret_cast<unsigned short*>(&h);
}
__device__ inline float bfbits2f(unsigned short u) {
    unsigned int x = ((unsigned int)u) << 16;
    return __uint_as_float(x);
}
// double-bf16 split: v ~= hi + lo with rel err ~2^-18
__device__ inline void split_bf(float v, unsigned short& hi, unsigned short& lo) {
    hi = f2bf_bits(v);
    float hf = bfbits2f(hi);
    lo = f2bf_bits(v - hf);
}

// ---------------------------------------------------------------------------
// Weff[l][o][i] = (wq-8)*scale + sum_r lora_b[l][o][r]*lora_a[l][r][i]
// stored as hi/lo bf16 pair. One block per (l, 8-row group) (proven r7).
// ---------------------------------------------------------------------------
__global__ __launch_bounds__(256)
void build_weff(const int* __restrict__ wq, const float* __restrict__ scales,
                const float* __restrict__ lora_a, const float* __restrict__ lora_b,
                bf16* __restrict__ weff_h, bf16* __restrict__ weff_l)
{
    const int bb = blockIdx.x;           // 18 * 128
    const int l  = bb >> 7;
    const int o0 = (bb & 127) * 8;
    __shared__ float bsh[8][32];
    {
        const int oo = threadIdx.x >> 5, rr = threadIdx.x & 31;
        bsh[oo][rr] = lora_b[((size_t)l * 1024 + o0 + oo) * 32 + rr];
    }
    __syncthreads();

    const float* abase = lora_a + (size_t)l * 32 * 1024;
    const int i0 = threadIdx.x * 4;      // 256 threads x 4 = 1024 i's
    float acc[8][4] = {};
    #pragma unroll 4
    for (int r = 0; r < 32; ++r) {
        float4 av = *reinterpret_cast<const float4*>(abase + (size_t)r * 1024 + i0);
        #pragma unroll
        for (int o = 0; o < 8; ++o) {
            const float br = bsh[o][r];
            acc[o][0] += br * av.x; acc[o][1] += br * av.y;
            acc[o][2] += br * av.z; acc[o][3] += br * av.w;
        }
    }
    #pragma unroll
    for (int o = 0; o < 8; ++o) {
        const size_t row = (size_t)l * 1024 + o0 + o;
        int4 q = *reinterpret_cast<const int4*>(wq + row * 1024 + i0);
        const float sc = scales[row * 64 + (i0 >> 4)];
        float w0 = (q.x - 8) * sc + acc[o][0];
        float w1 = (q.y - 8) * sc + acc[o][1];
        float w2 = (q.z - 8) * sc + acc[o][2];
        float w3 = (q.w - 8) * sc + acc[o][3];
        ushort4 uh, ul;
        split_bf(w0, uh.x, ul.x); split_bf(w1, uh.y, ul.y);
        split_bf(w2, uh.z, ul.z); split_bf(w3, uh.w, ul.w);
        *reinterpret_cast<ushort4*>(weff_h + row * 1024 + i0) = uh;
        *reinterpret_cast<ushort4*>(weff_l + row * 1024 + i0) = ul;
    }
}

// ---------------------------------------------------------------------------
// x f32 -> hi/lo bf16 pair
// ---------------------------------------------------------------------------
__global__ __launch_bounds__(256)
void cast_split(const float* __restrict__ x, bf16* __restrict__ yh, bf16* __restrict__ yl)
{
    size_t i = ((size_t)blockIdx.x * 256 + threadIdx.x) * 4;
    float4 v = *reinterpret_cast<const float4*>(x + i);
    ushort4 uh, ul;
    split_bf(v.x, uh.x, ul.x); split_bf(v.y, uh.y, ul.y);
    split_bf(v.z, uh.z, ul.z); split_bf(v.w, uh.w, ul.w);
    *reinterpret_cast<ushort4*>(yh + i) = uh;
    *reinterpret_cast<ushort4*>(yl + i) = ul;
}

// ---------------------------------------------------------------------------
// GEMM, double-bf16 operands, 3 MFMA products: acc += Ah*Wh + Ah*Wl + Al*Wh
// 256x256 tile, BK=32, 8 waves (2M x 4N, per-wave 128x64).
// NEW defer-stage schedule: ONE barrier per K-step, no lgkm drain:
//   vmcnt(0); bar; stage(kt+1 -> other buf); {24 ds_read || 96 MFMA}
// stage(kt+1) overwrites the buffer read at kt-1 — safe because barrier
// arrival implies each wave's reads(kt-1) were consumed by its MFMAs
// (compiler-inserted counted lgkm waits; DS completes in-order per wave).
// Post-loop lgkm(0)+barrier protects the epilogue LDS-scratch reuse.
// MODE 0: relu -> pair out;  MODE 1: +res -> pair out;  MODE 2: +res -> f32
// ---------------------------------------------------------------------------
#define TILE_E 8192            // elems per LDS tensor tile (256 rows x 32)
#define SET_E  (4 * TILE_E)    // Ah, Al, Wh, Wl

#define SCHED0 __builtin_amdgcn_sched_barrier(0)

template<int MODE>
__global__ __launch_bounds__(512)
void qgemm3(const bf16* __restrict__ AH, const bf16* __restrict__ AL,
            const bf16* __restrict__ WH, const bf16* __restrict__ WL,
            const float* __restrict__ bias,
            const bf16* __restrict__ RH, const bf16* __restrict__ RL,
            bf16* __restrict__ OH, bf16* __restrict__ OL,
            float* __restrict__ Of)
{
    __shared__ bf16 smem[2 * SET_E];   // 128 KiB

    // T1: chunked XCD swizzle, nwg = 256 (64 m-tiles x 4 n-tiles), 256%8==0.
    const int b  = blockIdx.x;
    const int sb = ((b & 7) << 5) | (b >> 3);
    const int n0 = (sb & 3) * 256;
    const int m0 = (sb >> 2) * 256;

    const int tid  = threadIdx.x;
    const int wave = tid >> 6;
    const int lane = tid & 63;
    const int wr = wave >> 2;          // 0..1  M half (128 rows)
    const int wc = wave & 3;           // 0..3  N strip (64 cols)

    const int rl = lane >> 2;          // staging: row within 16-row segment
    const int ps = lane & 3;           // staging: phys 16B slot
    const int fr = lane & 15;          // fragment row
    const int fq = lane >> 4;          // fragment k-chunk (16B unit)

    f32x4 acc[8][4] = {};

    // staging: wave w covers rows [w*32, w*32+32): 2 segments x 4 tensors
    // = 8 global_load_lds per wave per tile
    auto stage = [&](int buf, int k0) {
        bf16* base = smem + buf * SET_E;
        #pragma unroll
        for (int t = 0; t < 2; ++t) {
            int s = wave * 2 + t;                   // segment 0..15 (wave-uniform)
            int r = s * 16 + rl;                    // tile row
            int q = ps ^ (r & 3) ^ ((r >> 2) & 3);  // pre-swizzled global chunk
            size_t ga = (size_t)(m0 + r) * D_DIM + k0 + q * 8;
            size_t gb = (size_t)(n0 + r) * D_DIM + k0 + q * 8;
            bf16* dst = base + s * 512;             // wave-uniform; HW adds lane*16B
            gload_lds16(AH + ga, dst);
            gload_lds16(AL + ga, dst + TILE_E);
            gload_lds16(WH + gb, dst + 2 * TILE_E);
            gload_lds16(WL + gb, dst + 3 * TILE_E);
        }
    };

    // ---- prologue: tile 0 into buf 0
    stage(0, 0);

    #pragma unroll 1
    for (int kt = 0; kt < 32; ++kt) {
        const int cur = kt & 1;
        SCHED0;
        asm volatile("s_waitcnt vmcnt(0)" ::: "memory");   // stage(kt) landed
        SCHED0;
        __builtin_amdgcn_s_barrier();   // tile kt resident; reads(kt-1) consumed
        if (kt < 31)
            stage(cur ^ 1, (kt + 1) * 32);   // writes buf read at kt-1 — safe
        SCHED0;

        const bf16* tb = smem + cur * SET_E;
        bf16x8 wh[4], wl[4], ah[8], al[8];
        #pragma unroll
        for (int n = 0; n < 4; ++n) {
            int R = wc * 64 + n * 16 + fr;
            int p = fq ^ (R & 3) ^ ((R >> 2) & 3);
            int off = R * 32 + p * 8;
            wh[n] = *reinterpret_cast<const bf16x8*>(tb + 2 * TILE_E + off);
            wl[n] = *reinterpret_cast<const bf16x8*>(tb + 3 * TILE_E + off);
        }
        #pragma unroll
        for (int m = 0; m < 8; ++m) {
            int R = wr * 128 + m * 16 + fr;
            int p = fq ^ (R & 3) ^ ((R >> 2) & 3);
            int off = R * 32 + p * 8;
            ah[m] = *reinterpret_cast<const bf16x8*>(tb + off);
            al[m] = *reinterpret_cast<const bf16x8*>(tb + TILE_E + off);
        }

        __builtin_amdgcn_s_setprio(1);
        #pragma unroll
        for (int m = 0; m < 8; ++m)
            #pragma unroll
            for (int n = 0; n < 4; ++n) {
                acc[m][n] = __builtin_amdgcn_mfma_f32_16x16x32_bf16(ah[m], wh[n], acc[m][n], 0, 0, 0);
                acc[m][n] = __builtin_amdgcn_mfma_f32_16x16x32_bf16(ah[m], wl[n], acc[m][n], 0, 0, 0);
                acc[m][n] = __builtin_amdgcn_mfma_f32_16x16x32_bf16(al[m], wh[n], acc[m][n], 0, 0, 0);
            }
        __builtin_amdgcn_s_setprio(0);
    }

    // protect epilogue LDS-scratch reuse from any wave still reading buf1
    SCHED0;
    asm volatile("s_waitcnt lgkmcnt(0)" ::: "memory");
    SCHED0;
    __builtin_amdgcn_s_barrier();

    // ---- Epilogue via LDS transpose, 2 half-passes (per-wave 64x64 f32 =
    // 16 KiB x 8 waves = 128 KiB). Wave-private regions; DS in-order per wave.
    // C/D layout: col = lane&15 (=fr), row = (lane>>4)*4 + j.
    const int crow4 = (lane >> 4) * 4;
    float* cwave = reinterpret_cast<float*>(smem) + wave * 4096;
    const int rloc = lane >> 3;
    const int cloc = (lane & 7) * 8;

    #pragma unroll
    for (int half = 0; half < 2; ++half) {
        #pragma unroll
        for (int n = 0; n < 4; ++n) {
            const float bv = bias[n0 + wc * 64 + n * 16 + fr];
            const int lcol = n * 16 + fr;                 // local col 0..63
            const int chunk = lcol >> 2;
            #pragma unroll
            for (int mm = 0; mm < 4; ++mm) {
                const int m = half * 4 + mm;
                #pragma unroll
                for (int j = 0; j < 4; ++j) {
                    const int lrow = mm * 16 + crow4 + j; // local row 0..63
                    float v = acc[m][n][j] + bv;
                    if (MODE == 0) v = v > 0.f ? v : 0.f;
                    cwave[lrow * 64 + (chunk ^ (lrow & 15)) * 4 + (lcol & 3)] = v;
                }
            }
        }
        SCHED0;
        asm volatile("s_waitcnt lgkmcnt(0)" ::: "memory");
        SCHED0;

        #pragma unroll
        for (int pass = 0; pass < 8; ++pass) {
            const int lrow = pass * 8 + rloc;             // 0..63
            const int grow = m0 + wr * 128 + half * 64 + lrow;
            const size_t gbase = (size_t)grow * D_DIM + (n0 + wc * 64 + cloc);
            const int c0 = cloc >> 2;
            float4 v0 = *reinterpret_cast<const float4*>(&cwave[lrow * 64 + ((c0    ) ^ (lrow & 15)) * 4]);
            float4 v1 = *reinterpret_cast<const float4*>(&cwave[lrow * 64 + ((c0 + 1) ^ (lrow & 15)) * 4]);
            float vv[8] = {v0.x, v0.y, v0.z, v0.w, v1.x, v1.y, v1.z, v1.w};
            if (MODE != 0) {
                u16x8 rh = *reinterpret_cast<const u16x8*>(&RH[gbase]);
                u16x8 rl2 = *reinterpret_cast<const u16x8*>(&RL[gbase]);
                #pragma unroll
                for (int k = 0; k < 8; ++k)
                    vv[k] += bfbits2f(rh[k]) + bfbits2f(rl2[k]);
            }
            if (MODE == 2) {
                *reinterpret_cast<float4*>(&Of[gbase])     = make_float4(vv[0], vv[1], vv[2], vv[3]);
                *reinterpret_cast<float4*>(&Of[gbase + 4]) = make_float4(vv[4], vv[5], vv[6], vv[7]);
            } else {
                u16x8 ho, lo2;
                #pragma unroll
                for (int k = 0; k < 8; ++k) {
                    unsigned short h, l2;
                    split_bf(vv[k], h, l2);
                    ho[k] = h; lo2[k] = l2;
                }
                *reinterpret_cast<u16x8*>(&OH[gbase]) = ho;
                *reinterpret_cast<u16x8*>(&OL[gbase]) = lo2;
            }
        }
        SCHED0;
        asm volatile("s_waitcnt lgkmcnt(0)" ::: "memory");
        SCHED0;
    }
}

// ---------------------------------------------------------------------------
// LayerNorm on hi/lo pair. One block per row, 256 threads x 4 elems.
// ---------------------------------------------------------------------------
__global__ __launch_bounds__(256)
void ln_pair(const bf16* __restrict__ XH, const bf16* __restrict__ XL,
             bf16* __restrict__ YH, bf16* __restrict__ YL,
             const float* __restrict__ gamma, const float* __restrict__ beta)
{
    const int row = blockIdx.x;
    const int tid = threadIdx.x;
    const int lane = tid & 63;
    const int wave = tid >> 6;

    ushort4 uh = reinterpret_cast<const ushort4*>(XH + (size_t)row * D_DIM)[tid];
    ushort4 ul = reinterpret_cast<const ushort4*>(XL + (size_t)row * D_DIM)[tid];
    float v0 = bfbits2f(uh.x) + bfbits2f(ul.x);
    float v1 = bfbits2f(uh.y) + bfbits2f(ul.y);
    float v2 = bfbits2f(uh.z) + bfbits2f(ul.z);
    float v3 = bfbits2f(uh.w) + bfbits2f(ul.w);
    float s  = v0 + v1 + v2 + v3;
    float ss = v0 * v0 + v1 * v1 + v2 * v2 + v3 * v3;
    #pragma unroll
    for (int off = 32; off >= 1; off >>= 1) {
        s  += __shfl_xor(s, off, 64);
        ss += __shfl_xor(ss, off, 64);
    }
    __shared__ float red[8];
    if (lane == 0) { red[wave] = s; red[4 + wave] = ss; }
    __syncthreads();
    float S  = red[0] + red[1] + red[2] + red[3];
    float SS = red[4] + red[5] + red[6] + red[7];
    const float mean = S * (1.0f / D_DIM);
    const float var  = SS * (1.0f / D_DIM) - mean * mean;
    const float inv  = rsqrtf(var + 1e-5f);

    const int c0 = tid * 4;
    float y0 = (v0 - mean) * inv * gamma[c0 + 0] + beta[c0 + 0];
    float y1 = (v1 - mean) * inv * gamma[c0 + 1] + beta[c0 + 1];
    float y2 = (v2 - mean) * inv * gamma[c0 + 2] + beta[c0 + 2];
    float y3 = (v3 - mean) * inv * gamma[c0 + 3] + beta[c0 + 3];
    ushort4 oh, ol;
    split_bf(y0, oh.x, ol.x); split_bf(y1, oh.y, ol.y);
    split_bf(y2, oh.z, ol.z); split_bf(y3, oh.w, ol.w);
    reinterpret_cast<ushort4*>(YH + (size_t)row * D_DIM)[tid] = oh;
    reinterpret_cast<ushort4*>(YL + (size_t)row * D_DIM)[tid] = ol;
}

// ---------------------------------------------------------------------------
extern "C" void kernel_launch(void* const* d_in, const int* in_sizes, int n_in,
                              void* d_out, int out_size, void* d_ws, size_t ws_size,
                              hipStream_t stream)
{
    const float* x      = (const float*)d_in[0];
    const int*   wq     = (const int*)d_in[1];
    const float* scales = (const float*)d_in[2];
    const float* bias   = (const float*)d_in[3];
    const float* lora_a = (const float*)d_in[4];
    const float* lora_b = (const float*)d_in[5];
    const float* ln_g   = (const float*)d_in[6];
    const float* ln_b   = (const float*)d_in[7];
    float* out = (float*)d_out;

    char* ws = (char*)d_ws;
    const size_t W_ELEMS = (size_t)NLAYER * D_DIM * D_DIM;
    const size_t H_ELEMS = (size_t)B_ROWS * D_DIM;
    bf16* WHp = (bf16*)ws;
    bf16* WLp = WHp + W_ELEMS;
    bf16* HAh = WLp + W_ELEMS;
    bf16* HAl = HAh + H_ELEMS;
    bf16* HBh = HAl + H_ELEMS;
    bf16* HBl = HBh + H_ELEMS;
    // third activation pair lives in d_out (dead before final write)
    bf16* HCh = (bf16*)d_out;
    bf16* HCl = HCh + H_ELEMS;

    build_weff<<<dim3(NLAYER * 128), dim3(256), 0, stream>>>(wq, scales, lora_a, lora_b, WHp, WLp);
    cast_split<<<dim3((B_ROWS * D_DIM) / (256 * 4)), dim3(256), 0, stream>>>(x, HAh, HAl);

    dim3 ggrid(256);  // 64 m-tiles x 4 n-tiles, swizzled in-kernel
    for (int j = 0; j < 6; ++j) {
        const int l0 = 3 * j;
        const bf16* WH0 = WHp + (size_t)l0 * D_DIM * D_DIM;
        const bf16* WL0 = WLp + (size_t)l0 * D_DIM * D_DIM;
        const bf16* WH1 = WHp + (size_t)(l0 + 1) * D_DIM * D_DIM;
        const bf16* WL1 = WLp + (size_t)(l0 + 1) * D_DIM * D_DIM;
        const bf16* WH2 = WHp + (size_t)(l0 + 2) * D_DIM * D_DIM;
        const bf16* WL2 = WLp + (size_t)(l0 + 2) * D_DIM * D_DIM;
        const float* b0 = bias + (size_t)l0 * D_DIM;
        const float* b1 = bias + (size_t)(l0 + 1) * D_DIM;
        const float* b2 = bias + (size_t)(l0 + 2) * D_DIM;
        if (j < 5) {
            qgemm3<0><<<ggrid, 512, 0, stream>>>(HAh, HAl, WH0, WL0, b0, nullptr, nullptr, HBh, HBl, nullptr);
            qgemm3<0><<<ggrid, 512, 0, stream>>>(HBh, HBl, WH1, WL1, b1, nullptr, nullptr, HCh, HCl, nullptr);
            qgemm3<1><<<ggrid, 512, 0, stream>>>(HCh, HCl, WH2, WL2, b2, HAh, HAl, HBh, HBl, nullptr);
            ln_pair<<<dim3(B_ROWS), dim3(256), 0, stream>>>(HBh, HBl, HAh, HAl,
                                                            ln_g + (size_t)j * D_DIM, ln_b + (size_t)j * D_DIM);
        } else {
            qgemm3<0><<<ggrid, 512, 0, stream>>>(HAh, HAl, WH0, WL0, b0, nullptr, nullptr, HCh, HCl, nullptr);
            qgemm3<0><<<ggrid, 512, 0, stream>>>(HCh, HCl, WH1, WL1, b1, nullptr, nullptr, HBh, HBl, nullptr);
            qgemm3<2><<<ggrid, 512, 0, stream>>>(HBh, HBl, WH2, WL2, b2, HAh, HAl, nullptr, nullptr, out);
        }
    }
}